// Round 8
// baseline (552.224 us; speedup 1.0000x reference)
//
#include <hip/hip_runtime.h>
#include <hip/hip_cooperative_groups.h>
#include <cmath>

namespace cg = cooperative_groups;

#define Nn 200000
#define NWP 512
#define SEGSZ 256
#define NSEG2 782          // ceil(200000/256)
#define CAP 1024           // per-row candidate capacity (typ. bucket ~390)
#define N4TOT 12800064     // (256 + 256*200000)/4  -> fills ALL of d_out exactly
#define FA_END 1920000
#define FB_END 3840000
#define FC_END 5760000

struct HistS { int hist[NWP]; int found; };
struct ScatS { int wps[SEGSZ]; int sc_offs[NWP + 1]; };
struct OwnerS {
    int nlist[CAP]; float svals[CAP]; unsigned char vbit[CAP];
    float ltile[64 * 65]; float q_s[64]; float red2[256]; int redc[256];
    float pbuf[64]; float Msh, Ssh, scale_sh;
};
struct DenseS { float q_s[64]; float redm[4], reds[4]; float Msh, Ssh; float pbuf2[256]; };
union SMu { HistS a; ScatS c; OwnerS d; DenseS e; };

__device__ __forceinline__ bool mask_at(const void* m, size_t idx, int isbyte) {
    if (isbyte) return ((const unsigned char*)m)[idx] != 0;
    return ((const unsigned int*)m)[idx] != 0u;
}

__device__ __forceinline__ void fill_range(float4* __restrict__ p, int s4, int e4,
                                           int idx0, int stride) {
    const float4 z = make_float4(0.f, 0.f, 0.f, 0.f);
    for (int i = s4 + idx0; i < e4; i += stride) p[i] = z;
}

// One kernel, 5 phases. phase<0: cooperative single-launch with grid syncs.
// phase==k (0..4): run only phase k (fallback mode; kernel boundaries act as syncs).
__global__ __launch_bounds__(256) void coopK(
    const float* __restrict__ q, const float* __restrict__ lib,
    const void* __restrict__ mask, const int* __restrict__ lib_wp,
    const int* __restrict__ wp_id, const int* __restrict__ action_id,
    const float* __restrict__ wp_prior, const float* __restrict__ act_emb,
    const float* __restrict__ W1, const float* __restrict__ b1,
    const float* __restrict__ W2, const float* __restrict__ b2,
    const float* __restrict__ log_tau, const float* __restrict__ plw,
    float* __restrict__ out, char* __restrict__ ws, int phase) {
    __shared__ SMu sm;
    int* flag    = (int*)(ws);
    int* suff    = (int*)(ws + 1024);
    int* ovfl    = (int*)(ws + 2048);
    int* offs_g  = (int*)(ws + 4096);        // 513 ints
    int* tot     = (int*)(ws + 8192);        // 512 ints
    int* seg_cnt = (int*)(ws + 16384);       // 782*512 ints = 1601536 B
    int* bucket  = (int*)(ws + 1622016);     // 200000 ints
    float* ctxws = (float*)(ws + 2424832);   // 256*64 floats
    float* pv    = (float*)(ws + 2490368);   // 256*CAP floats = 1 MB
    float* attnbuf = out + 256;
    float4* fillp = (float4*)out;            // fill covers logits+attn exactly

    int nblk = gridDim.x, bid = blockIdx.x, t = threadIdx.x;

    // ================= phase 0: seg-hist + mask detect + fill A =================
    if (phase < 0 || phase == 0) {
        for (int seg = bid; seg < NSEG2; seg += nblk) {
            sm.a.hist[t] = 0; sm.a.hist[t + 256] = 0;
            __syncthreads();
            int n = seg * SEGSZ + t;
            if (n < Nn) {
                int w = lib_wp[n]; w = min(max(w, 0), NWP - 1);
                atomicAdd(&sm.a.hist[w], 1);
            }
            __syncthreads();
            seg_cnt[seg * NWP + t] = sm.a.hist[t];
            seg_cnt[seg * NWP + t + 256] = sm.a.hist[t + 256];
            __syncthreads();
        }
        if (bid == nblk - 1) {
            if (t == 0) sm.a.found = 0;
            __syncthreads();
            int f = 0;
            const unsigned int* mw = (const unsigned int*)mask;
            for (int i = t; i < 4096; i += 256) {
                unsigned int x = mw[i];
                if (x >= 2u && x != 0x3F800000u) f = 1;   // byte bools leak into high bytes
            }
            if (f) atomicOr(&sm.a.found, 1);
            __syncthreads();
            if (t == 0) flag[0] = sm.a.found;
        }
        fill_range(fillp, 0, FA_END, bid * 256 + t, nblk * 256);
        if (phase < 0) { __threadfence(); cg::this_grid().sync(); }
    }

    // ================= phase 1: per-waypoint column scan + fill B =================
    if (phase < 0 || phase == 1) {
        int wv = t >> 6, lane = t & 63;
        for (int wp = bid * 4 + wv; wp < NWP; wp += nblk * 4) {
            int vals[13];
            int base = lane * 13;
            int lt = 0;
#pragma unroll
            for (int i = 0; i < 13; ++i) {
                int seg = base + i;
                int v = (seg < NSEG2) ? seg_cnt[seg * NWP + wp] : 0;
                vals[i] = v; lt += v;
            }
            int pre = lt;
            for (int off = 1; off < 64; off <<= 1) {
                int x = __shfl_up(pre, off, 64);
                if (lane >= off) pre += x;
            }
            int excl = pre - lt;
            int total = __shfl(pre, 63, 64);
            int run = excl;
#pragma unroll
            for (int i = 0; i < 13; ++i) {
                int seg = base + i;
                if (seg < NSEG2) { seg_cnt[seg * NWP + wp] = run; run += vals[i]; }
            }
            if (lane == 0) tot[wp] = total;
        }
        fill_range(fillp, FA_END, FB_END, bid * 256 + t, nblk * 256);
        if (phase < 0) { __threadfence(); cg::this_grid().sync(); }
    }

    // ================= phase 2: offs scan (per block) + stable scatter + fill C =================
    if (phase < 0 || phase == 2) {
        if (t < 64) {
            int vals[8]; int lt = 0;
#pragma unroll
            for (int i = 0; i < 8; ++i) { int v = tot[t * 8 + i]; vals[i] = v; lt += v; }
            int pre = lt;
            for (int off = 1; off < 64; off <<= 1) {
                int x = __shfl_up(pre, off, 64);
                if (t >= off) pre += x;
            }
            int excl = pre - lt, run = excl;
#pragma unroll
            for (int i = 0; i < 8; ++i) { sm.c.sc_offs[t * 8 + i] = run; run += vals[i]; }
            if (t == 63) sm.c.sc_offs[NWP] = pre;
        }
        __syncthreads();
        if (bid == 0) {
            offs_g[t] = sm.c.sc_offs[t];
            offs_g[t + 256] = sm.c.sc_offs[t + 256];
            if (t == 0) offs_g[NWP] = sm.c.sc_offs[NWP];
        }
        for (int seg = bid; seg < NSEG2; seg += nblk) {
            int n = seg * SEGSZ + t;
            int w = -1;
            if (n < Nn) { w = lib_wp[n]; w = min(max(w, 0), NWP - 1); }
            sm.c.wps[t] = w;
            __syncthreads();
            if (n < Nn) {
                int r = 0;
                for (int j = 0; j < t; ++j) r += (sm.c.wps[j] == w) ? 1 : 0;
                bucket[sm.c.sc_offs[w] + seg_cnt[seg * NWP + w] + r] = n;
            }
            __syncthreads();
        }
        fill_range(fillp, FB_END, FC_END, bid * 256 + t, nblk * 256);
        if (phase < 0) { __threadfence(); cg::this_grid().sync(); }
    }

    // ================= phase 3: owner sparse flash softmax+ctx (blocks <256) + fill D =================
    if (phase < 0 || phase == 3) {
        if (bid < 256) {
            int b = bid;
            int isb = flag[0];
            int w = wp_id[b]; w = min(max(w, 0), NWP - 1);
            int off = offs_g[w], sz = offs_g[w + 1] - off;
            bool ov = sz > CAP;
            int c = 0;
            if (!ov) {
                for (int i = t; i < sz; i += 256) {
                    int n = bucket[off + i];
                    sm.d.nlist[i] = n;
                    bool vld = !mask_at(mask, (size_t)b * Nn + n, isb);
                    sm.d.vbit[i] = vld ? 1 : 0;
                    c += vld ? 1 : 0;
                }
            } else {
                for (int i = t; i < sz; i += 256) {
                    int n = bucket[off + i];
                    c += mask_at(mask, (size_t)b * Nn + n, isb) ? 0 : 1;
                }
            }
            sm.d.redc[t] = c;
            __syncthreads();
            for (int s2 = 128; s2 > 0; s2 >>= 1) {
                if (t < s2) sm.d.redc[t] += sm.d.redc[t + s2];
                __syncthreads();
            }
            int cnt = sm.d.redc[0];
            bool sf = cnt >= 8;
            if (t == 0) { suff[b] = sf ? 1 : 0; ovfl[b] = ov ? 1 : 0; }
            __syncthreads();
            if (sf && !ov) {
                if (t < 64) sm.d.q_s[t] = q[b * 64 + t];
                if (t == 0) { sm.d.Msh = -INFINITY; sm.d.Ssh = 0.f; }
                float tau = expf(log_tau[0]);
                tau = fminf(fmaxf(tau, 1e-3f), 10.0f);
                float inv_tau = 1.0f / tau;
                int d = t & 63, g = t >> 6;
                float ctxp = 0.f;
                __syncthreads();
                for (int c0 = 0; c0 < sz; c0 += 64) {
                    int cn = min(64, sz - c0);
                    int i = t >> 2, part = t & 3;
                    if (i < cn) {
                        int n_i = sm.d.nlist[c0 + i];
                        const float* src = &lib[(size_t)n_i * 64 + part * 16];
                        float4 v0 = *(const float4*)&src[0];
                        float4 v1 = *(const float4*)&src[4];
                        float4 v2 = *(const float4*)&src[8];
                        float4 v3 = *(const float4*)&src[12];
                        float* dst = &sm.d.ltile[i * 65 + part * 16];
                        dst[0] = v0.x;  dst[1] = v0.y;  dst[2] = v0.z;  dst[3] = v0.w;
                        dst[4] = v1.x;  dst[5] = v1.y;  dst[6] = v1.z;  dst[7] = v1.w;
                        dst[8] = v2.x;  dst[9] = v2.y;  dst[10] = v2.z; dst[11] = v2.w;
                        dst[12] = v3.x; dst[13] = v3.y; dst[14] = v3.z; dst[15] = v3.w;
                    }
                    __syncthreads();
                    float s = -INFINITY;
                    if (t < 64) {
                        if (t < cn) {
                            if (sm.d.vbit[c0 + t]) {
                                float acc = 0.f;
#pragma unroll
                                for (int dd = 0; dd < 64; ++dd)
                                    acc = fmaf(sm.d.q_s[dd], sm.d.ltile[t * 65 + dd], acc);
                                s = acc * inv_tau;
                            }
                            sm.d.svals[c0 + t] = s;
                        }
                        float m = s;
#pragma unroll
                        for (int o = 1; o < 64; o <<= 1) m = fmaxf(m, __shfl_xor(m, o, 64));
                        float e = (s > -INFINITY) ? expf(s - m) : 0.f;
#pragma unroll
                        for (int o = 1; o < 64; o <<= 1) e += __shfl_xor(e, o, 64);
                        if (t == 0) {
                            float newM = fmaxf(sm.d.Msh, m);
                            if (newM > -INFINITY) {
                                float scl = expf(sm.d.Msh - newM);
                                sm.d.Ssh = sm.d.Ssh * scl + e * expf(m - newM);
                                sm.d.Msh = newM;
                                sm.d.scale_sh = scl;
                            } else {
                                sm.d.scale_sh = 1.f;
                            }
                        }
                    }
                    __syncthreads();
                    ctxp *= sm.d.scale_sh;
                    if (t < 64) sm.d.pbuf[t] = (s > -INFINITY) ? expf(s - sm.d.Msh) : 0.f;
                    __syncthreads();
                    for (int i2 = g; i2 < cn; i2 += 4)
                        ctxp = fmaf(sm.d.pbuf[i2], sm.d.ltile[i2 * 65 + d], ctxp);
                    __syncthreads();
                }
                float M = sm.d.Msh, invS = 1.0f / sm.d.Ssh;
                sm.d.red2[t] = ctxp;
                __syncthreads();
                if (t < 64)
                    ctxws[b * 64 + t] = (sm.d.red2[t] + sm.d.red2[64 + t] +
                                         sm.d.red2[128 + t] + sm.d.red2[192 + t]) * invS;
                for (int i = t; i < sz; i += 256) {
                    float s2 = sm.d.svals[i];
                    pv[(size_t)b * CAP + i] = (s2 > -INFINITY) ? expf(s2 - M) * invS : 0.f;
                }
            }
        }
        {
            int nf = (nblk > 256) ? (nblk - 256) : nblk;
            int fb = (nblk > 256) ? (bid - 256) : bid;
            if (fb >= 0) fill_range(fillp, FC_END, N4TOT, fb * 256 + t, nf * 256);
        }
        if (phase < 0) { __threadfence(); cg::this_grid().sync(); }
    }

    // ================= phase 4: scatter p (or dense fallback) + MLP head =================
    if (phase < 0 || phase == 4) {
        if (bid < 256) {
            int b = bid;
            int sfb = suff[b], ov = ovfl[b];
            int w = wp_id[b]; w = min(max(w, 0), NWP - 1);
            if (sfb && !ov) {
                int off = offs_g[w], sz = offs_g[w + 1] - off;
                for (int i = t; i < sz; i += 256)
                    attnbuf[(size_t)b * Nn + bucket[off + i]] = pv[(size_t)b * CAP + i];
            } else {
                // dense-general evaluator (rare): full reference formula incl. wp filter
                if (t < 64) sm.e.q_s[t] = q[b * 64 + t];
                if (t == 0) { sm.e.Msh = -INFINITY; sm.e.Ssh = 0.f; }
                int isb = flag[0];
                float tau = expf(log_tau[0]);
                tau = fminf(fmaxf(tau, 1e-3f), 10.0f);
                float inv_tau = 1.0f / tau;
                __syncthreads();
                for (int c0 = 0; c0 < Nn; c0 += 256) {
                    int n = c0 + t;
                    float s = -INFINITY;
                    if (n < Nn) {
                        bool mk = mask_at(mask, (size_t)b * Nn + n, isb);
                        bool wpm = (lib_wp[n] == wp_id[b]);
                        if (!mk && !(sfb && !wpm)) {
                            float acc = 0.f;
#pragma unroll
                            for (int dd = 0; dd < 64; dd += 4) {
                                float4 v = *(const float4*)&lib[(size_t)n * 64 + dd];
                                acc = fmaf(sm.e.q_s[dd], v.x, acc);
                                acc = fmaf(sm.e.q_s[dd + 1], v.y, acc);
                                acc = fmaf(sm.e.q_s[dd + 2], v.z, acc);
                                acc = fmaf(sm.e.q_s[dd + 3], v.w, acc);
                            }
                            s = acc * inv_tau;
                        }
                        attnbuf[(size_t)b * Nn + n] = s;
                    }
                    float m = s;
#pragma unroll
                    for (int o = 1; o < 64; o <<= 1) m = fmaxf(m, __shfl_xor(m, o, 64));
                    float e = (s > -INFINITY) ? expf(s - m) : 0.f;
#pragma unroll
                    for (int o = 1; o < 64; o <<= 1) e += __shfl_xor(e, o, 64);
                    if ((t & 63) == 0) { sm.e.redm[t >> 6] = m; sm.e.reds[t >> 6] = e; }
                    __syncthreads();
                    if (t == 0) {
                        for (int wv2 = 0; wv2 < 4; ++wv2) {
                            float m2 = sm.e.redm[wv2], e2 = sm.e.reds[wv2];
                            if (m2 > -INFINITY) {
                                if (m2 > sm.e.Msh) {
                                    sm.e.Ssh = sm.e.Ssh * expf(sm.e.Msh - m2) + e2;
                                    sm.e.Msh = m2;
                                } else {
                                    sm.e.Ssh += e2 * expf(m2 - sm.e.Msh);
                                }
                            }
                        }
                    }
                    __syncthreads();
                }
                float M = sm.e.Msh, invS = 1.0f / sm.e.Ssh;
                int d = t & 63, g = t >> 6;
                float ctxp = 0.f;
                for (int c0 = 0; c0 < Nn; c0 += 256) {
                    int n = c0 + t;
                    float p = 0.f;
                    if (n < Nn) {
                        float s = attnbuf[(size_t)b * Nn + n];
                        p = (s > -INFINITY) ? expf(s - M) * invS : 0.f;
                        attnbuf[(size_t)b * Nn + n] = p;
                    }
                    sm.e.pbuf2[t] = p;
                    __syncthreads();
                    int lim = min(256, Nn - c0);
                    for (int i2 = g; i2 < lim; i2 += 4) {
                        float p2 = sm.e.pbuf2[i2];
                        if (p2 != 0.f) ctxp = fmaf(p2, lib[(size_t)(c0 + i2) * 64 + d], ctxp);
                    }
                    __syncthreads();
                }
                sm.e.pbuf2[t] = ctxp;
                __syncthreads();
                if (t < 64)
                    ctxws[b * 64 + t] = sm.e.pbuf2[t] + sm.e.pbuf2[64 + t] +
                                        sm.e.pbuf2[128 + t] + sm.e.pbuf2[192 + t];
            }
            __syncthreads();
            if (t < 64) {
                int j = t;
                float ctx = ctxws[b * 64 + j];
                float acc = b1[j];
                int aid = action_id[b];
                for (int i = 0; i < 64; ++i) acc = fmaf(q[b * 64 + i], W1[i * 64 + j], acc);
                for (int i = 0; i < 64; ++i)
                    acc = fmaf(__shfl(ctx, i, 64), W1[(64 + i) * 64 + j], acc);
                for (int i = 0; i < 6; ++i)
                    acc = fmaf(act_emb[aid * 6 + i], W1[(128 + i) * 64 + j], acc);
                float h1 = 0.5f * acc * (1.0f + erff(acc * 0.70710678118654752f));
                float v = h1 * W2[j];
#pragma unroll
                for (int o = 1; o < 64; o <<= 1) v += __shfl_xor(v, o, 64);
                if (j == 0) {
                    float pr = fminf(fmaxf(wp_prior[b], 1e-3f), 1.0f - 1e-3f);
                    float pl = logf(pr) - log1pf(-pr);
                    out[b] = v + b2[0] + plw[0] * pl;
                }
            }
        }
    }
}

extern "C" void kernel_launch(void* const* d_in, const int* in_sizes, int n_in,
                              void* d_out, int out_size, void* d_ws, size_t ws_size,
                              hipStream_t stream) {
    const float* q = (const float*)d_in[0];
    const float* lib = (const float*)d_in[1];
    const void* mask = d_in[2];
    const int* lib_wp = (const int*)d_in[3];
    const int* wp_id = (const int*)d_in[4];
    const int* action_id = (const int*)d_in[5];
    const float* wp_prior = (const float*)d_in[6];
    const float* act_emb = (const float*)d_in[7];
    const float* W1 = (const float*)d_in[8];
    const float* b1 = (const float*)d_in[9];
    const float* W2 = (const float*)d_in[10];
    const float* b2 = (const float*)d_in[11];
    const float* log_tau = (const float*)d_in[12];
    const float* plw = (const float*)d_in[13];
    float* out = (float*)d_out;
    char* ws = (char*)d_ws;

    int maxPerCU = 0;
    hipError_t qerr = hipOccupancyMaxActiveBlocksPerMultiprocessor(&maxPerCU, coopK, 256, 0);
    if (qerr != hipSuccess || maxPerCU < 1) maxPerCU = 1;
    int nblk = maxPerCU * 256;           // 256 CUs on gfx950
    if (nblk > 1024) nblk = 1024;
    if (nblk < 256) nblk = 256;
    int phase = -1;

    void* args[] = {(void*)&q, (void*)&lib, (void*)&mask, (void*)&lib_wp, (void*)&wp_id,
                    (void*)&action_id, (void*)&wp_prior, (void*)&act_emb, (void*)&W1,
                    (void*)&b1, (void*)&W2, (void*)&b2, (void*)&log_tau, (void*)&plw,
                    (void*)&out, (void*)&ws, (void*)&phase};
    hipError_t err = hipLaunchCooperativeKernel((const void*)coopK, dim3(nblk), dim3(256),
                                                args, 0, stream);
    if (err != hipSuccess) {
        // fallback: 5 sequential launches, kernel boundaries provide the syncs
        for (int p = 0; p < 5; ++p)
            coopK<<<dim3(1024), 256, 0, stream>>>(q, lib, mask, lib_wp, wp_id, action_id,
                                                  wp_prior, act_emb, W1, b1, W2, b2,
                                                  log_tau, plw, out, ws, p);
    }
}

// Round 9
// 357.514 us; speedup vs baseline: 1.5446x; 1.5446x over previous
//
#include <hip/hip_runtime.h>
#include <cmath>

#define Nn 200000
#define CAP 1024      // total candidate capacity (typ. ~390)
#define CAPQ 512      // per-quarter list capacity
#define QSZ 50000     // Nn/4
#define NCHK 196      // fill chunks: 196*256 float4 >= 50000

__device__ __forceinline__ bool mask_at(const void* m, size_t idx, int isbyte) {
    if (isbyte) return ((const unsigned char*)m)[idx] != 0;
    return ((const unsigned int*)m)[idx] != 0u;
}

// One block per row b. Waves 0-3: zero-fill row (work-stealing). Waves 4-7: scan
// lib_wp quarters for same-waypoint candidates; wave 4 then merges (stable,
// ascending n), counts valid, runs single-wave flash softmax + ctx. One join
// barrier; then scatter p over the zeros (or dense fallback) + MLP head.
__global__ __launch_bounds__(512) void kmain(
    const float* __restrict__ q, const float* __restrict__ lib,
    const void* __restrict__ mask, const int* __restrict__ lib_wp,
    const int* __restrict__ wp_id, const int* __restrict__ action_id,
    const float* __restrict__ wp_prior, const float* __restrict__ act_emb,
    const float* __restrict__ W1, const float* __restrict__ b1,
    const float* __restrict__ W2, const float* __restrict__ b2,
    const float* __restrict__ log_tau, const float* __restrict__ plw,
    float* __restrict__ out) {
    __shared__ int qlist[4 * CAPQ];
    __shared__ int qcnt[4];
    __shared__ int qflag[4];
    __shared__ int nlist[CAP];
    __shared__ float svals[CAP];
    __shared__ unsigned char vbit[CAP];
    __shared__ float ltile[64 * 65];      // stride 65: conflict-free
    __shared__ float q_s[64];
    __shared__ float pbuf[64];
    __shared__ float ctx_s[64];
    __shared__ float redm[8], reds[8];
    __shared__ float pbuf2[512];
    __shared__ float MshD, SshD;
    __shared__ float Mf, iSf;
    __shared__ int isb_s, dense_s, suff_s, sz_s;
    __shared__ int fill_next;

    int b = blockIdx.x, t = threadIdx.x;
    int wv = t >> 6, lane = t & 63;
    float* attnrow = out + 256 + (size_t)b * Nn;

    if (t < 4) { qflag[t] = 0; qcnt[t] = 0; }
    if (t == 4) fill_next = 0;
    __syncthreads();                                   // barrier 1 (init)

    int wpb = wp_id[b];

    // ---- LDS work-stealing zero-fill of this row (any wave can contribute) ----
    auto do_fill = [&]() {
        float4* rowp = (float4*)attnrow;               // 16B-aligned
        const float4 z = make_float4(0.f, 0.f, 0.f, 0.f);
        for (;;) {
            int chunk = 0;
            if (lane == 0) chunk = atomicAdd(&fill_next, 1);
            chunk = __shfl(chunk, 0, 64);
            if (chunk >= NCHK) break;
            int base = chunk * 256 + lane;
#pragma unroll
            for (int k = 0; k < 4; ++k) {
                int i = base + k * 64;
                if (i < 50000) rowp[i] = z;
            }
        }
    };

    if (wv < 4) {
        do_fill();
    } else {
        int qq = wv - 4;
        if (qq == 0) {
            // mask storage-format detect (byte bools vs word)
            const unsigned int* mw = (const unsigned int*)mask;
            int f = 0;
            for (int i = lane; i < 4096; i += 64) {
                unsigned int x = mw[i];
                if (x >= 2u && x != 0x3F800000u) f = 1;
            }
            int anyf = (__ballot(f != 0) != 0ull) ? 1 : 0;
            if (lane == 0) isb_s = anyf;
        }
        // ---- quarter scan: stable ballot-compaction of same-wp candidates ----
        int qs = qq * QSZ, qe = qs + QSZ;
        int cnt = 0;
        for (int c0 = qs; c0 < qe; c0 += 64) {
            int n = c0 + lane;
            bool match = (n < qe) && (lib_wp[n] == wpb);
            unsigned long long bal = __ballot(match);
            unsigned long long ltm = (lane == 0) ? 0ull : (~0ull >> (64 - lane));
            int pos = cnt + (int)__popcll(bal & ltm);
            if (match && pos < CAPQ) qlist[qq * CAPQ + pos] = n;
            cnt += (int)__popcll(bal);
        }
        if (lane == 0) qcnt[qq] = cnt;
        if (qq != 0) {
            __hip_atomic_store(&qflag[qq], 1, __ATOMIC_RELEASE, __HIP_MEMORY_SCOPE_WORKGROUP);
            do_fill();
        } else {
            // ---- wave 4: wait for quarter lists ----
            for (int qx = 1; qx < 4; ++qx)
                while (__hip_atomic_load(&qflag[qx], __ATOMIC_ACQUIRE,
                                         __HIP_MEMORY_SCOPE_WORKGROUP) == 0)
                    __builtin_amdgcn_s_sleep(1);
            asm volatile("s_waitcnt lgkmcnt(0)" ::: "memory");
            int isb = isb_s;
            int c0n = qcnt[0], c1n = qcnt[1], c2n = qcnt[2], c3n = qcnt[3];
            int sz = c0n + c1n + c2n + c3n;
            bool ov = (sz > CAP) || (c0n > CAPQ) || (c1n > CAPQ) || (c2n > CAPQ) ||
                      (c3n > CAPQ);
            int cntv = 0;
            if (!ov) {
                int bases[4] = {0, c0n, c0n + c1n, c0n + c1n + c2n};
                int cs[4] = {c0n, c1n, c2n, c3n};
                for (int qx = 0; qx < 4; ++qx)
                    for (int i = lane; i < cs[qx]; i += 64)
                        nlist[bases[qx] + i] = qlist[qx * CAPQ + i];
                asm volatile("s_waitcnt lgkmcnt(0)" ::: "memory");
                for (int i = lane; i < sz; i += 64) {
                    int n = nlist[i];
                    bool v = !mask_at(mask, (size_t)b * Nn + n, isb);
                    vbit[i] = v ? 1 : 0;
                    cntv += v ? 1 : 0;
                }
            } else {
                // rare overflow: count by dense rescan
                for (int n = lane; n < Nn; n += 64)
                    if (lib_wp[n] == wpb && !mask_at(mask, (size_t)b * Nn + n, isb)) cntv++;
            }
#pragma unroll
            for (int o = 1; o < 64; o <<= 1) cntv += __shfl_xor(cntv, o, 64);
            bool sf = cntv >= 8;
            if (lane == 0) {
                suff_s = sf ? 1 : 0;
                dense_s = (!sf || ov) ? 1 : 0;
                sz_s = sz;
            }
            if (sf && !ov) {
                // ---- single-wave flash softmax + ctx over candidates ----
                q_s[lane] = q[b * 64 + lane];
                float tau = expf(log_tau[0]);
                tau = fminf(fmaxf(tau, 1e-3f), 10.0f);
                float inv_tau = 1.0f / tau;
                float Ms = -INFINITY, Ss = 0.f, ctxp = 0.f;
                for (int cc = 0; cc < sz; cc += 64) {
                    int cn = min(64, sz - cc);
                    if (lane < cn) {
                        int n_i = nlist[cc + lane];
                        const float4* src = (const float4*)&lib[(size_t)n_i * 64];
                        float* dst = &ltile[lane * 65];
#pragma unroll
                        for (int p4 = 0; p4 < 16; ++p4) {
                            float4 v = src[p4];
                            dst[p4 * 4] = v.x; dst[p4 * 4 + 1] = v.y;
                            dst[p4 * 4 + 2] = v.z; dst[p4 * 4 + 3] = v.w;
                        }
                    }
                    asm volatile("s_waitcnt lgkmcnt(0)" ::: "memory");
                    float s = -INFINITY;
                    if (lane < cn && vbit[cc + lane]) {
                        float acc = 0.f;
#pragma unroll
                        for (int dd = 0; dd < 64; ++dd)
                            acc = fmaf(q_s[dd], ltile[lane * 65 + dd], acc);
                        s = acc * inv_tau;
                    }
                    if (lane < cn) svals[cc + lane] = s;
                    float m = s;
#pragma unroll
                    for (int o = 1; o < 64; o <<= 1) m = fmaxf(m, __shfl_xor(m, o, 64));
                    float e = (s > -INFINITY) ? expf(s - m) : 0.f;
#pragma unroll
                    for (int o = 1; o < 64; o <<= 1) e += __shfl_xor(e, o, 64);
                    float scl = 1.f;
                    float newM = fmaxf(Ms, m);
                    if (newM > -INFINITY) {
                        scl = expf(Ms - newM);         // Ms=-inf -> 0 (safe)
                        Ss = Ss * scl + e * expf(m - newM);
                        Ms = newM;
                    }
                    ctxp *= scl;                       // flash rescale
                    pbuf[lane] = (s > -INFINITY) ? expf(s - Ms) : 0.f;
                    asm volatile("s_waitcnt lgkmcnt(0)" ::: "memory");
                    for (int i2 = 0; i2 < cn; ++i2)
                        ctxp = fmaf(pbuf[i2], ltile[i2 * 65 + lane], ctxp);
                }
                float invS = 1.0f / Ss;
                ctx_s[lane] = ctxp * invS;
                if (lane == 0) { Mf = Ms; iSf = invS; }
            }
            do_fill();                                 // help finish the row fill
        }
    }
    __threadfence();                                   // drain fill stores (WAW)
    __syncthreads();                                   // barrier 2 (join)

    int dense = dense_s;                               // uniform per block
    if (!dense) {
        // ---- scatter p over the zero-filled row ----
        float M = Mf, invS = iSf;
        int sz = sz_s;
        for (int i = t; i < sz; i += 512) {
            float s2 = svals[i];
            attnrow[nlist[i]] = (s2 > -INFINITY) ? expf(s2 - M) * invS : 0.f;
        }
    } else {
        // ---- dense fallback (rare/never): full reference formula ----
        int sfb = suff_s, isb = isb_s;
        if (t < 64) q_s[t] = q[b * 64 + t];
        if (t == 0) { MshD = -INFINITY; SshD = 0.f; }
        float tau = expf(log_tau[0]);
        tau = fminf(fmaxf(tau, 1e-3f), 10.0f);
        float inv_tau = 1.0f / tau;
        __syncthreads();
        for (int c0 = 0; c0 < Nn; c0 += 512) {
            int n = c0 + t;
            float s = -INFINITY;
            if (n < Nn) {
                bool mk = mask_at(mask, (size_t)b * Nn + n, isb);
                bool wpm = (lib_wp[n] == wpb);
                if (!mk && !(sfb && !wpm)) {
                    float acc = 0.f;
#pragma unroll
                    for (int dd = 0; dd < 64; dd += 4) {
                        float4 v = *(const float4*)&lib[(size_t)n * 64 + dd];
                        acc = fmaf(q_s[dd], v.x, acc);
                        acc = fmaf(q_s[dd + 1], v.y, acc);
                        acc = fmaf(q_s[dd + 2], v.z, acc);
                        acc = fmaf(q_s[dd + 3], v.w, acc);
                    }
                    s = acc * inv_tau;
                }
                attnrow[n] = s;
            }
            float m = s;
#pragma unroll
            for (int o = 1; o < 64; o <<= 1) m = fmaxf(m, __shfl_xor(m, o, 64));
            float e = (s > -INFINITY) ? expf(s - m) : 0.f;
#pragma unroll
            for (int o = 1; o < 64; o <<= 1) e += __shfl_xor(e, o, 64);
            if (lane == 0) { redm[wv] = m; reds[wv] = e; }
            __syncthreads();
            if (t == 0) {
                for (int g = 0; g < 8; ++g) {
                    float m2 = redm[g], e2 = reds[g];
                    if (m2 > -INFINITY) {
                        if (m2 > MshD) { SshD = SshD * expf(MshD - m2) + e2; MshD = m2; }
                        else           { SshD += e2 * expf(m2 - MshD); }
                    }
                }
            }
            __syncthreads();
        }
        float M = MshD, invS = 1.0f / SshD;
        int d = t & 63, g = t >> 6;
        float ctxp = 0.f;
        for (int c0 = 0; c0 < Nn; c0 += 512) {
            int n = c0 + t;
            float p = 0.f;
            if (n < Nn) {
                float s = attnrow[n];
                p = (s > -INFINITY) ? expf(s - M) * invS : 0.f;
                attnrow[n] = p;
            }
            pbuf2[t] = p;
            __syncthreads();
            int lim = min(512, Nn - c0);
            for (int i2 = g; i2 < lim; i2 += 8) {
                float p2 = pbuf2[i2];
                if (p2 != 0.f) ctxp = fmaf(p2, lib[(size_t)(c0 + i2) * 64 + d], ctxp);
            }
            __syncthreads();
        }
        pbuf2[t] = ctxp;
        __syncthreads();
        if (t < 64) {
            float cacc = 0.f;
            for (int g2 = 0; g2 < 8; ++g2) cacc += pbuf2[g2 * 64 + t];
            ctx_s[t] = cacc;
        }
        __syncthreads();
    }

    // ---- MLP head + prior (threads 0..63 = wave 0) ----
    if (t < 64) {
        int j = t;
        float ctx = ctx_s[j];
        float acc = b1[j];
        int aid = action_id[b];
        for (int i = 0; i < 64; ++i) acc = fmaf(q[b * 64 + i], W1[i * 64 + j], acc);
        for (int i = 0; i < 64; ++i) acc = fmaf(__shfl(ctx, i, 64), W1[(64 + i) * 64 + j], acc);
        for (int i = 0; i < 6; ++i) acc = fmaf(act_emb[aid * 6 + i], W1[(128 + i) * 64 + j], acc);
        float h1 = 0.5f * acc * (1.0f + erff(acc * 0.70710678118654752f));
        float v = h1 * W2[j];
#pragma unroll
        for (int o = 1; o < 64; o <<= 1) v += __shfl_xor(v, o, 64);
        if (j == 0) {
            float pr = fminf(fmaxf(wp_prior[b], 1e-3f), 1.0f - 1e-3f);
            float pl = logf(pr) - log1pf(-pr);
            out[b] = v + b2[0] + plw[0] * pl;
        }
    }
}

extern "C" void kernel_launch(void* const* d_in, const int* in_sizes, int n_in,
                              void* d_out, int out_size, void* d_ws, size_t ws_size,
                              hipStream_t stream) {
    const float* q = (const float*)d_in[0];
    const float* lib = (const float*)d_in[1];
    const void* mask = d_in[2];
    const int* lib_wp = (const int*)d_in[3];
    const int* wp_id = (const int*)d_in[4];
    const int* action_id = (const int*)d_in[5];
    const float* wp_prior = (const float*)d_in[6];
    const float* act_emb = (const float*)d_in[7];
    const float* W1 = (const float*)d_in[8];
    const float* b1 = (const float*)d_in[9];
    const float* W2 = (const float*)d_in[10];
    const float* b2 = (const float*)d_in[11];
    const float* log_tau = (const float*)d_in[12];
    const float* plw = (const float*)d_in[13];
    float* out = (float*)d_out;
    (void)d_ws; (void)ws_size; (void)in_sizes; (void)n_in; (void)out_size;

    kmain<<<dim3(256), 512, 0, stream>>>(q, lib, mask, lib_wp, wp_id, action_id, wp_prior,
                                         act_emb, W1, b1, W2, b2, log_tau, plw, out);
}

// Round 10
// 94.509 us; speedup vs baseline: 5.8431x; 3.7829x over previous
//
#include <hip/hip_runtime.h>
#include <cmath>

#define Nn 200000
#define CAP 1024      // merged candidate capacity (typ. ~390)
#define CAPQ 256      // per-wave (eighth) capacity
#define ESZ 25000     // ints per wave segment (Nn/8)
#define EI4 6250      // int4 per segment
#define NIT 98        // ceil(6250/64)
#define NF4 50000     // float4 per row (200000 floats)

__device__ __forceinline__ bool mask_at(const void* m, size_t idx, int isbyte) {
    if (isbyte) return ((const unsigned char*)m)[idx] != 0;
    return ((const unsigned int*)m)[idx] != 0u;
}

// One block per row b.
// Phase A (all 8 waves): int4-vectorized stable compaction scan of lib_wp eighths.
// Phase B: wave 0 merges + flash softmax + ctx; waves 1-7 zero-fill the row.
// Phase C: scatter p over zeros (or dense fallback) + MLP head.
__global__ __launch_bounds__(512) void kmain(
    const float* __restrict__ q, const float* __restrict__ lib,
    const void* __restrict__ mask, const int* __restrict__ lib_wp,
    const int* __restrict__ wp_id, const int* __restrict__ action_id,
    const float* __restrict__ wp_prior, const float* __restrict__ act_emb,
    const float* __restrict__ W1, const float* __restrict__ b1,
    const float* __restrict__ W2, const float* __restrict__ b2,
    const float* __restrict__ log_tau, const float* __restrict__ plw,
    float* __restrict__ out) {
    __shared__ int qlist[8 * CAPQ];
    __shared__ int qcnt[8];
    __shared__ int nlist[CAP];
    __shared__ float svals[CAP];
    __shared__ unsigned char vbit[CAP];
    __shared__ float ltile[64 * 65];      // stride 65: conflict-free
    __shared__ float q_s[64], pbuf[64], ctx_s[64];
    __shared__ float redm[8], reds[8];
    __shared__ float pbuf2[512];
    __shared__ int redci[512];
    __shared__ float MshD, SshD, Mf, iSf;
    __shared__ int isb_s, dense_s, sz_s;

    int b = blockIdx.x, t = threadIdx.x;
    int wv = t >> 6, lane = t & 63;
    float* attnrow = out + 256 + (size_t)b * Nn;
    int wpb = wp_id[b];

    // ================= phase A: parallel stable candidate scan =================
    if (wv == 0) {
        // mask storage-format detect (byte bools vs word)
        const uint4* mw4 = (const uint4*)mask;
        int f = 0;
        for (int i = lane; i < 1024; i += 64) {
            uint4 x = mw4[i];
            if ((x.x >= 2u && x.x != 0x3F800000u) || (x.y >= 2u && x.y != 0x3F800000u) ||
                (x.z >= 2u && x.z != 0x3F800000u) || (x.w >= 2u && x.w != 0x3F800000u))
                f = 1;
        }
        unsigned long long bal = __ballot(f != 0);
        if (lane == 0) isb_s = bal ? 1 : 0;
    }
    {
        const int4* seg = (const int4*)(lib_wp + wv * ESZ);
        int cnt = 0;
        int pad = wpb ^ 1;                 // guaranteed != wpb
#pragma unroll 4
        for (int it = 0; it < NIT; ++it) {
            int i = it * 64 + lane;
            int4 v = (i < EI4) ? seg[i] : make_int4(pad, pad, pad, pad);
            int m0 = (v.x == wpb) ? 1 : 0;
            int m1 = (v.y == wpb) ? 1 : 0;
            int m2 = (v.z == wpb) ? 1 : 0;
            int m3 = (v.w == wpb) ? 1 : 0;
            int mc = m0 + m1 + m2 + m3;
            unsigned long long anyb = __ballot(mc != 0);   // wave-uniform
            if (anyb) {
                int inc = mc;
#pragma unroll
                for (int o = 1; o < 64; o <<= 1) {
                    int x = __shfl_up(inc, o, 64);
                    if (lane >= o) inc += x;
                }
                int excl = inc - mc;
                int wtot = __shfl(inc, 63, 64);
                int pos = cnt + excl;
                int nb = wv * ESZ + i * 4;
                if (m0) { if (pos < CAPQ) qlist[wv * CAPQ + pos] = nb;     pos++; }
                if (m1) { if (pos < CAPQ) qlist[wv * CAPQ + pos] = nb + 1; pos++; }
                if (m2) { if (pos < CAPQ) qlist[wv * CAPQ + pos] = nb + 2; pos++; }
                if (m3) { if (pos < CAPQ) qlist[wv * CAPQ + pos] = nb + 3; pos++; }
                cnt += wtot;
            }
        }
        if (lane == 0) qcnt[wv] = cnt;
    }
    __syncthreads();                                   // barrier 1

    // ================= phase B: wave 0 computes; waves 1-7 fill =================
    if (wv == 0) {
        int isb = isb_s;
        int cs[8];
        int sz = 0;
        bool ov = false;
#pragma unroll
        for (int k = 0; k < 8; ++k) {
            int c = qcnt[k];
            cs[k] = c; sz += c;
            if (c > CAPQ) ov = true;
        }
        if (sz > CAP) ov = true;
        int cntv = 0;
        if (!ov) {
            int base = 0;
#pragma unroll
            for (int k = 0; k < 8; ++k) {
                for (int i = lane; i < cs[k]; i += 64) nlist[base + i] = qlist[k * CAPQ + i];
                base += cs[k];
            }
            asm volatile("s_waitcnt lgkmcnt(0)" ::: "memory");
            for (int i = lane; i < sz; i += 64) {
                int n = nlist[i];
                bool v = !mask_at(mask, (size_t)b * Nn + n, isb);
                vbit[i] = v ? 1 : 0;
                cntv += v ? 1 : 0;
            }
#pragma unroll
            for (int o = 1; o < 64; o <<= 1) cntv += __shfl_xor(cntv, o, 64);
        }
        bool sf = (!ov) && (cntv >= 8);
        if (lane == 0) { dense_s = sf ? 0 : 1; sz_s = sz; }
        if (sf) {
            // ---- single-wave flash softmax + ctx over candidates (R9-verified) ----
            q_s[lane] = q[b * 64 + lane];
            float tau = expf(log_tau[0]);
            tau = fminf(fmaxf(tau, 1e-3f), 10.0f);
            float inv_tau = 1.0f / tau;
            float Ms = -INFINITY, Ss = 0.f, ctxp = 0.f;
            for (int cc = 0; cc < sz; cc += 64) {
                int cn = min(64, sz - cc);
                if (lane < cn) {
                    int n_i = nlist[cc + lane];
                    const float4* src = (const float4*)&lib[(size_t)n_i * 64];
                    float* dst = &ltile[lane * 65];
#pragma unroll
                    for (int p4 = 0; p4 < 16; ++p4) {
                        float4 v = src[p4];
                        dst[p4 * 4] = v.x; dst[p4 * 4 + 1] = v.y;
                        dst[p4 * 4 + 2] = v.z; dst[p4 * 4 + 3] = v.w;
                    }
                }
                asm volatile("s_waitcnt lgkmcnt(0)" ::: "memory");
                float s = -INFINITY;
                if (lane < cn && vbit[cc + lane]) {
                    float acc = 0.f;
#pragma unroll
                    for (int dd = 0; dd < 64; ++dd)
                        acc = fmaf(q_s[dd], ltile[lane * 65 + dd], acc);
                    s = acc * inv_tau;
                }
                if (lane < cn) svals[cc + lane] = s;
                float m = s;
#pragma unroll
                for (int o = 1; o < 64; o <<= 1) m = fmaxf(m, __shfl_xor(m, o, 64));
                float e = (s > -INFINITY) ? expf(s - m) : 0.f;
#pragma unroll
                for (int o = 1; o < 64; o <<= 1) e += __shfl_xor(e, o, 64);
                float scl = 1.f;
                float newM = fmaxf(Ms, m);
                if (newM > -INFINITY) {
                    scl = expf(Ms - newM);             // Ms=-inf -> 0 (safe)
                    Ss = Ss * scl + e * expf(m - newM);
                    Ms = newM;
                }
                ctxp *= scl;                           // flash rescale
                pbuf[lane] = (s > -INFINITY) ? expf(s - Ms) : 0.f;
                asm volatile("s_waitcnt lgkmcnt(0)" ::: "memory");
                for (int i2 = 0; i2 < cn; ++i2)
                    ctxp = fmaf(pbuf[i2], ltile[i2 * 65 + lane], ctxp);
            }
            float invS = 1.0f / Ss;
            ctx_s[lane] = ctxp * invS;
            if (lane == 0) { Mf = Ms; iSf = invS; }
        }
    } else {
        // ---- static zero-fill of this row (7 waves, coalesced float4) ----
        float4* rowp = (float4*)attnrow;               // 16B-aligned
        const float4 z = make_float4(0.f, 0.f, 0.f, 0.f);
        const int share = 7143;                        // ceil(50000/7)
        int s0 = (wv - 1) * share;
        int e0 = min(NF4, s0 + share);
#pragma unroll 4
        for (int i = s0 + lane; i < e0; i += 64) rowp[i] = z;
    }
    __syncthreads();                                   // barrier 2 (drains vmcnt)

    // ================= phase C: scatter or dense fallback, then MLP =================
    int dense = dense_s;                               // uniform per block
    if (!dense) {
        float M = Mf, invS = iSf;
        int sz = sz_s;
        for (int i = t; i < sz; i += 512) {
            float s2 = svals[i];
            attnrow[nlist[i]] = (s2 > -INFINITY) ? expf(s2 - M) * invS : 0.f;
        }
    } else {
        // ---- dense fallback (rare/never): recompute count, then full formula ----
        int isb = isb_s;
        int cntd = 0;
        for (int c0 = 0; c0 < Nn; c0 += 512) {
            int n = c0 + t;
            if (n < Nn && lib_wp[n] == wpb && !mask_at(mask, (size_t)b * Nn + n, isb))
                cntd++;
        }
        redci[t] = cntd;
        __syncthreads();
        for (int s2 = 256; s2 > 0; s2 >>= 1) {
            if (t < s2) redci[t] += redci[t + s2];
            __syncthreads();
        }
        int sfb = (redci[0] >= 8) ? 1 : 0;
        if (t < 64) q_s[t] = q[b * 64 + t];
        if (t == 0) { MshD = -INFINITY; SshD = 0.f; }
        float tau = expf(log_tau[0]);
        tau = fminf(fmaxf(tau, 1e-3f), 10.0f);
        float inv_tau = 1.0f / tau;
        __syncthreads();
        for (int c0 = 0; c0 < Nn; c0 += 512) {
            int n = c0 + t;
            float s = -INFINITY;
            if (n < Nn) {
                bool mk = mask_at(mask, (size_t)b * Nn + n, isb);
                bool wpm = (lib_wp[n] == wpb);
                if (!mk && !(sfb && !wpm)) {
                    float acc = 0.f;
#pragma unroll
                    for (int dd = 0; dd < 64; dd += 4) {
                        float4 v = *(const float4*)&lib[(size_t)n * 64 + dd];
                        acc = fmaf(q_s[dd], v.x, acc);
                        acc = fmaf(q_s[dd + 1], v.y, acc);
                        acc = fmaf(q_s[dd + 2], v.z, acc);
                        acc = fmaf(q_s[dd + 3], v.w, acc);
                    }
                    s = acc * inv_tau;
                }
                attnrow[n] = s;
            }
            float m = s;
#pragma unroll
            for (int o = 1; o < 64; o <<= 1) m = fmaxf(m, __shfl_xor(m, o, 64));
            float e = (s > -INFINITY) ? expf(s - m) : 0.f;
#pragma unroll
            for (int o = 1; o < 64; o <<= 1) e += __shfl_xor(e, o, 64);
            if (lane == 0) { redm[wv] = m; reds[wv] = e; }
            __syncthreads();
            if (t == 0) {
                for (int g = 0; g < 8; ++g) {
                    float m2 = redm[g], e2 = reds[g];
                    if (m2 > -INFINITY) {
                        if (m2 > MshD) { SshD = SshD * expf(MshD - m2) + e2; MshD = m2; }
                        else           { SshD += e2 * expf(m2 - MshD); }
                    }
                }
            }
            __syncthreads();
        }
        float M = MshD, invS = 1.0f / SshD;
        int d = t & 63, g = t >> 6;
        float ctxp = 0.f;
        for (int c0 = 0; c0 < Nn; c0 += 512) {
            int n = c0 + t;
            float p = 0.f;
            if (n < Nn) {
                float s = attnrow[n];
                p = (s > -INFINITY) ? expf(s - M) * invS : 0.f;
                attnrow[n] = p;
            }
            pbuf2[t] = p;
            __syncthreads();
            int lim = min(512, Nn - c0);
            for (int i2 = g; i2 < lim; i2 += 8) {
                float p2 = pbuf2[i2];
                if (p2 != 0.f) ctxp = fmaf(p2, lib[(size_t)(c0 + i2) * 64 + d], ctxp);
            }
            __syncthreads();
        }
        pbuf2[t] = ctxp;
        __syncthreads();
        if (t < 64) {
            float cacc = 0.f;
            for (int g2 = 0; g2 < 8; ++g2) cacc += pbuf2[g2 * 64 + t];
            ctx_s[t] = cacc;
        }
        __syncthreads();
    }

    // ---- MLP head + prior (threads 0..63 = wave 0) ----
    if (t < 64) {
        int j = t;
        float ctx = ctx_s[j];
        float acc = b1[j];
        int aid = action_id[b];
        for (int i = 0; i < 64; ++i) acc = fmaf(q[b * 64 + i], W1[i * 64 + j], acc);
        for (int i = 0; i < 64; ++i) acc = fmaf(__shfl(ctx, i, 64), W1[(64 + i) * 64 + j], acc);
        for (int i = 0; i < 6; ++i) acc = fmaf(act_emb[aid * 6 + i], W1[(128 + i) * 64 + j], acc);
        float h1 = 0.5f * acc * (1.0f + erff(acc * 0.70710678118654752f));
        float v = h1 * W2[j];
#pragma unroll
        for (int o = 1; o < 64; o <<= 1) v += __shfl_xor(v, o, 64);
        if (j == 0) {
            float pr = fminf(fmaxf(wp_prior[b], 1e-3f), 1.0f - 1e-3f);
            float pl = logf(pr) - log1pf(-pr);
            out[b] = v + b2[0] + plw[0] * pl;
        }
    }
}

extern "C" void kernel_launch(void* const* d_in, const int* in_sizes, int n_in,
                              void* d_out, int out_size, void* d_ws, size_t ws_size,
                              hipStream_t stream) {
    const float* q = (const float*)d_in[0];
    const float* lib = (const float*)d_in[1];
    const void* mask = d_in[2];
    const int* lib_wp = (const int*)d_in[3];
    const int* wp_id = (const int*)d_in[4];
    const int* action_id = (const int*)d_in[5];
    const float* wp_prior = (const float*)d_in[6];
    const float* act_emb = (const float*)d_in[7];
    const float* W1 = (const float*)d_in[8];
    const float* b1 = (const float*)d_in[9];
    const float* W2 = (const float*)d_in[10];
    const float* b2 = (const float*)d_in[11];
    const float* log_tau = (const float*)d_in[12];
    const float* plw = (const float*)d_in[13];
    float* out = (float*)d_out;
    (void)d_ws; (void)ws_size; (void)in_sizes; (void)n_in; (void)out_size;

    kmain<<<dim3(256), 512, 0, stream>>>(q, lib, mask, lib_wp, wp_id, action_id, wp_prior,
                                         act_emb, W1, b1, W2, b2, log_tau, plw, out);
}